// Round 6
// baseline (657.704 us; speedup 1.0000x reference)
//
#include <hip/hip_runtime.h>

#define NT 512   // T
#define NB 128   // B
#define ND 256   // D
#define NH 256   // H

typedef _Float16 h2 __attribute__((ext_vector_type(2)));

#if __has_builtin(__builtin_amdgcn_fdot2)
#define DOT2(a, b, c) __builtin_amdgcn_fdot2((a), (b), (c), false)
#else
#define DOT2(a, b, c) (fmaf((float)(a)[0], (float)(b)[0], \
                        fmaf((float)(a)[1], (float)(b)[1], (c))))
#endif

// ---------------------------------------------------------------------------
// Phase 1: Z = X @ Wi^T + bh.  Register-tiled fp32 GEMM (unchanged, proven).
// ---------------------------------------------------------------------------
__global__ __launch_bounds__(256) void zprep_kernel(
    const float* __restrict__ X, const float* __restrict__ Wi,
    const float* __restrict__ bh, float* __restrict__ Z)
{
    __shared__ float xsT[64][68];   // [k][m]
    __shared__ float wsT[64][68];   // [k][j]
    const int tid = threadIdx.x;
    const int tm  = tid & 15, tj = tid >> 4;
    const int m0  = blockIdx.x * 64;
    const int j0  = blockIdx.y * 64;
    const int sm  = tid >> 2, kq = tid & 3;

    float acc[4][4] = {};

    for (int c = 0; c < 4; ++c) {
        const int k0 = c * 64;
        const float* xr = X  + (size_t)(m0 + sm) * ND + k0 + kq * 16;
        const float* wr = Wi + (size_t)(j0 + sm) * ND + k0 + kq * 16;
        #pragma unroll
        for (int i = 0; i < 4; ++i) {
            const float4 xv = *(const float4*)(xr + i * 4);
            const float4 wv = *(const float4*)(wr + i * 4);
            const int kk = kq * 16 + i * 4;
            xsT[kk + 0][sm] = xv.x; xsT[kk + 1][sm] = xv.y;
            xsT[kk + 2][sm] = xv.z; xsT[kk + 3][sm] = xv.w;
            wsT[kk + 0][sm] = wv.x; wsT[kk + 1][sm] = wv.y;
            wsT[kk + 2][sm] = wv.z; wsT[kk + 3][sm] = wv.w;
        }
        __syncthreads();

        #pragma unroll 8
        for (int k = 0; k < 64; ++k) {
            const float4 x4 = *(const float4*)&xsT[k][tm * 4];
            const float4 w4 = *(const float4*)&wsT[k][tj * 4];
            acc[0][0] = fmaf(x4.x, w4.x, acc[0][0]);
            acc[0][1] = fmaf(x4.x, w4.y, acc[0][1]);
            acc[0][2] = fmaf(x4.x, w4.z, acc[0][2]);
            acc[0][3] = fmaf(x4.x, w4.w, acc[0][3]);
            acc[1][0] = fmaf(x4.y, w4.x, acc[1][0]);
            acc[1][1] = fmaf(x4.y, w4.y, acc[1][1]);
            acc[1][2] = fmaf(x4.y, w4.z, acc[1][2]);
            acc[1][3] = fmaf(x4.y, w4.w, acc[1][3]);
            acc[2][0] = fmaf(x4.z, w4.x, acc[2][0]);
            acc[2][1] = fmaf(x4.z, w4.y, acc[2][1]);
            acc[2][2] = fmaf(x4.z, w4.z, acc[2][2]);
            acc[2][3] = fmaf(x4.z, w4.w, acc[2][3]);
            acc[3][0] = fmaf(x4.w, w4.x, acc[3][0]);
            acc[3][1] = fmaf(x4.w, w4.y, acc[3][1]);
            acc[3][2] = fmaf(x4.w, w4.z, acc[3][2]);
            acc[3][3] = fmaf(x4.w, w4.w, acc[3][3]);
        }
        __syncthreads();
    }

    const float4 b4 = *(const float4*)&bh[j0 + tj * 4];
    #pragma unroll
    for (int r = 0; r < 4; ++r) {
        float4 o;
        o.x = acc[r][0] + b4.x; o.y = acc[r][1] + b4.y;
        o.z = acc[r][2] + b4.z; o.w = acc[r][3] + b4.w;
        *(float4*)&Z[(size_t)(m0 + tm * 4 + r) * NH + j0 + tj * 4] = o;
    }
}

// ---------------------------------------------------------------------------
// Phase 2: recurrence, fp16 dot2 / fp32 accumulate.
// TWO batch rows per WG (64 WGs): each streamed weight load feeds both rows'
// dots, halving chip-wide L2 weight traffic (the R3 bottleneck: 16 MB/step
// through 14.4 KB/cyc L2 ~= 1150 cyc/step). Structure otherwise IDENTICAL
// to the proven R3 kernel: ks=tid&3 owns a 64-wide k-slice of outputs
// j0=2jb, 2jb+1; h double-buffered in LDS (slice ks at h2-index ks*36 ->
// conflict-free broadcast b128 reads); quad shfl_xor(1,2) reduce; one
// barrier/step; unconditional z prefetch; immediate global store (the R4
// deferred-store variant regressed). No asm register pinning (3 failed
// rounds) -- amortization is algorithmic, not residency-dependent.
// ---------------------------------------------------------------------------
__global__ __launch_bounds__(512, 2) void rnn_step_kernel(
    float* __restrict__ ZO,
    const float* __restrict__ h0,
    const float* __restrict__ Wh)
{
    __shared__ h2 hb[2][2][4 * 36];   // [buf][row][padded slices]
    const int b0  = blockIdx.x * 2;
    const int tid = threadIdx.x;
    const int ks  = tid & 3;
    const int jb  = tid >> 2;
    const int j0  = jb * 2;

    // Wh rows j0, j0+1, k-slice [ks*64, ks*64+64) -> packed half2 (R3 pattern)
    h2 w0p[32], w1p[32];
    {
        const float* r0 = Wh + (size_t)j0 * NH + ks * 64;
        const float* r1 = r0 + NH;
        #pragma unroll
        for (int i = 0; i < 16; ++i) {
            const float4 a = *(const float4*)(r0 + 4 * i);
            const float4 c = *(const float4*)(r1 + 4 * i);
            w0p[2*i+0] = h2{(_Float16)a.x, (_Float16)a.y};
            w0p[2*i+1] = h2{(_Float16)a.z, (_Float16)a.w};
            w1p[2*i+0] = h2{(_Float16)c.x, (_Float16)c.y};
            w1p[2*i+1] = h2{(_Float16)c.z, (_Float16)c.w};
        }
    }

    if (tid < 256) {
        const int r = tid >> 7, i = tid & 127;
        const float2 hp = *(const float2*)(h0 + (size_t)(b0 + r) * NH + i * 2);
        hb[0][r][(i >> 5) * 36 + (i & 31)] =
            h2{(_Float16)hp.x, (_Float16)hp.y};
    }

    float2 zA = *(const float2*)(ZO + (size_t)(b0 + 0) * NH + j0);   // t = 0
    float2 zB = *(const float2*)(ZO + (size_t)(b0 + 1) * NH + j0);
    __syncthreads();

    int cur = 0;
    for (int t = 0; t < NT; ++t) {
        // this thread's 32 half2 of h, both rows (R3's proven read pattern)
        h2 hA[32], hB[32];
        const h2* pA = &hb[cur][0][ks * 36];
        const h2* pB = &hb[cur][1][ks * 36];
        #pragma unroll
        for (int i = 0; i < 8; ++i) {
            *(float4*)&hA[4 * i] = *(const float4*)&pA[4 * i];
            *(float4*)&hB[4 * i] = *(const float4*)&pB[4 * i];
        }

        // prefetch z for t+1 (hides under the dot)
        float2 zAn = zA, zBn = zB;
        if (t + 1 < NT) {
            zAn = *(const float2*)(ZO + ((size_t)(t+1) * NB + b0 + 0) * NH + j0);
            zBn = *(const float2*)(ZO + ((size_t)(t+1) * NB + b0 + 1) * NH + j0);
        }

        // 8 chains: each weight value used by BOTH rows (the amortization)
        float a0A = 0.f, a1A = 0.f, a0B = 0.f, a1B = 0.f;
        float c0A = 0.f, c1A = 0.f, c0B = 0.f, c1B = 0.f;
        #pragma unroll
        for (int i = 0; i < 16; ++i) {
            a0A = DOT2(w0p[i],      hA[i],      a0A);
            a0B = DOT2(w0p[i],      hB[i],      a0B);
            a1A = DOT2(w1p[i],      hA[i],      a1A);
            a1B = DOT2(w1p[i],      hB[i],      a1B);
            c0A = DOT2(w0p[i + 16], hA[i + 16], c0A);
            c0B = DOT2(w0p[i + 16], hB[i + 16], c0B);
            c1A = DOT2(w1p[i + 16], hA[i + 16], c1A);
            c1B = DOT2(w1p[i + 16], hB[i + 16], c1B);
        }
        float s0A = a0A + c0A, s1A = a1A + c1A;
        float s0B = a0B + c0B, s1B = a1B + c1B;

        s0A += __shfl_xor(s0A, 1); s1A += __shfl_xor(s1A, 1);
        s0B += __shfl_xor(s0B, 1); s1B += __shfl_xor(s1B, 1);
        s0A += __shfl_xor(s0A, 2); s1A += __shfl_xor(s1A, 2);
        s0B += __shfl_xor(s0B, 2); s1B += __shfl_xor(s1B, 2);

        if (ks == 0) {
            const float p0 = zA.x + s0A, p1 = zA.y + s1A;
            const float q0 = zB.x + s0B, q1 = zB.y + s1B;
            const float hA0 = 1.0f / (1.0f + __expf(-p0));
            const float hA1 = 1.0f / (1.0f + __expf(-p1));
            const float hB0 = 1.0f / (1.0f + __expf(-q0));
            const float hB1 = 1.0f / (1.0f + __expf(-q1));
            hb[cur ^ 1][0][(jb >> 5) * 36 + (jb & 31)] =
                h2{(_Float16)hA0, (_Float16)hA1};
            hb[cur ^ 1][1][(jb >> 5) * 36 + (jb & 31)] =
                h2{(_Float16)hB0, (_Float16)hB1};
            *(float2*)(ZO + ((size_t)t * NB + b0 + 0) * NH + j0) =
                make_float2(hA0, hA1);
            *(float2*)(ZO + ((size_t)t * NB + b0 + 1) * NH + j0) =
                make_float2(hB0, hB1);
        }
        zA = zAn; zB = zBn;
        __syncthreads();
        cur ^= 1;
    }
}

extern "C" void kernel_launch(void* const* d_in, const int* in_sizes, int n_in,
                              void* d_out, int out_size, void* d_ws, size_t ws_size,
                              hipStream_t stream) {
    const float* X  = (const float*)d_in[0];
    const float* h0 = (const float*)d_in[1];
    const float* Wi = (const float*)d_in[2];
    const float* Wh = (const float*)d_in[3];
    const float* bh = (const float*)d_in[4];
    float* out = (float*)d_out;

    dim3 zgrid((NT * NB) / 64, NH / 64);
    zprep_kernel<<<zgrid, 256, 0, stream>>>(X, Wi, bh, out);
    rnn_step_kernel<<<NB / 2, 512, 0, stream>>>(out, h0, Wh);
}

// Round 7
// 495.221 us; speedup vs baseline: 1.3281x; 1.3281x over previous
//
#include <hip/hip_runtime.h>

#define NT 512   // T
#define NB 128   // B
#define ND 256   // D
#define NH 256   // H

typedef _Float16 h2 __attribute__((ext_vector_type(2)));
typedef unsigned int u4 __attribute__((ext_vector_type(4)));

#if __has_builtin(__builtin_amdgcn_fdot2)
#define DOT2(a, b, c) __builtin_amdgcn_fdot2((a), (b), (c), false)
#else
#define DOT2(a, b, c) (fmaf((float)(a)[0], (float)(b)[0], \
                        fmaf((float)(a)[1], (float)(b)[1], (c))))
#endif

// ---------------------------------------------------------------------------
// Phase 1: Z = X @ Wi^T + bh.  Register-tiled fp32 GEMM (unchanged, proven).
// ---------------------------------------------------------------------------
__global__ __launch_bounds__(256) void zprep_kernel(
    const float* __restrict__ X, const float* __restrict__ Wi,
    const float* __restrict__ bh, float* __restrict__ Z)
{
    __shared__ float xsT[64][68];   // [k][m]
    __shared__ float wsT[64][68];   // [k][j]
    const int tid = threadIdx.x;
    const int tm  = tid & 15, tj = tid >> 4;
    const int m0  = blockIdx.x * 64;
    const int j0  = blockIdx.y * 64;
    const int sm  = tid >> 2, kq = tid & 3;

    float acc[4][4] = {};

    for (int c = 0; c < 4; ++c) {
        const int k0 = c * 64;
        const float* xr = X  + (size_t)(m0 + sm) * ND + k0 + kq * 16;
        const float* wr = Wi + (size_t)(j0 + sm) * ND + k0 + kq * 16;
        #pragma unroll
        for (int i = 0; i < 4; ++i) {
            const float4 xv = *(const float4*)(xr + i * 4);
            const float4 wv = *(const float4*)(wr + i * 4);
            const int kk = kq * 16 + i * 4;
            xsT[kk + 0][sm] = xv.x; xsT[kk + 1][sm] = xv.y;
            xsT[kk + 2][sm] = xv.z; xsT[kk + 3][sm] = xv.w;
            wsT[kk + 0][sm] = wv.x; wsT[kk + 1][sm] = wv.y;
            wsT[kk + 2][sm] = wv.z; wsT[kk + 3][sm] = wv.w;
        }
        __syncthreads();

        #pragma unroll 8
        for (int k = 0; k < 64; ++k) {
            const float4 x4 = *(const float4*)&xsT[k][tm * 4];
            const float4 w4 = *(const float4*)&wsT[k][tj * 4];
            acc[0][0] = fmaf(x4.x, w4.x, acc[0][0]);
            acc[0][1] = fmaf(x4.x, w4.y, acc[0][1]);
            acc[0][2] = fmaf(x4.x, w4.z, acc[0][2]);
            acc[0][3] = fmaf(x4.x, w4.w, acc[0][3]);
            acc[1][0] = fmaf(x4.y, w4.x, acc[1][0]);
            acc[1][1] = fmaf(x4.y, w4.y, acc[1][1]);
            acc[1][2] = fmaf(x4.y, w4.z, acc[1][2]);
            acc[1][3] = fmaf(x4.y, w4.w, acc[1][3]);
            acc[2][0] = fmaf(x4.z, w4.x, acc[2][0]);
            acc[2][1] = fmaf(x4.z, w4.y, acc[2][1]);
            acc[2][2] = fmaf(x4.z, w4.z, acc[2][2]);
            acc[2][3] = fmaf(x4.z, w4.w, acc[2][3]);
            acc[3][0] = fmaf(x4.w, w4.x, acc[3][0]);
            acc[3][1] = fmaf(x4.w, w4.y, acc[3][1]);
            acc[3][2] = fmaf(x4.w, w4.z, acc[3][2]);
            acc[3][3] = fmaf(x4.w, w4.w, acc[3][3]);
        }
        __syncthreads();
    }

    const float4 b4 = *(const float4*)&bh[j0 + tj * 4];
    #pragma unroll
    for (int r = 0; r < 4; ++r) {
        float4 o;
        o.x = acc[r][0] + b4.x; o.y = acc[r][1] + b4.y;
        o.z = acc[r][2] + b4.z; o.w = acc[r][3] + b4.w;
        *(float4*)&Z[(size_t)(m0 + tm * 4 + r) * NH + j0 + tj * 4] = o;
    }
}

// ---------------------------------------------------------------------------
// Phase 2: recurrence, fp16 dot2 / fp32 accumulate. One WG / batch row,
// 1024 threads (16 waves). ks=tid&7 owns a 32-wide k-slice of outputs
// j0=2jb, 2jb+1 (jb=tid>>3). Per-thread state: 32 packed-half2 weight
// dwords + 16 h dwords + 4 acc ~= 70 VGPRs, under the 128 cap from
// __launch_bounds__(1024,4) (exactly 1 block/CU). R1's spill is explained:
// no min-waves arg -> compiler targeted 2 blocks/CU -> 64-VGPR cap. Here
// the allocator has 2x headroom, so loop-invariant weights stay resident.
// h double-buffered in LDS; slice ks at h2-offset ks*24 (48 B stride:
// 16-B aligned b128 reads, slice starts on 8 distinct banks, broadcast
// within 8-lane groups). Reduce over 8 ks lanes: in-wave shfl_xor(1,2,4).
// One barrier/step, unconditional z prefetch, immediate store (all proven
// in R3; R4's deferral regressed).
// ---------------------------------------------------------------------------
__global__ __launch_bounds__(1024, 4) void rnn_step_kernel(
    float* __restrict__ ZO,
    const float* __restrict__ h0,
    const float* __restrict__ Wh)
{
    __shared__ __align__(16) h2 hb[2][8 * 24];   // 8 slices x 16 h2, pad to 24
    const int b   = blockIdx.x;
    const int tid = threadIdx.x;
    const int ks  = tid & 7;
    const int jb  = tid >> 3;
    const int j0  = jb * 2;

    // Wh rows j0, j0+1, k-slice [ks*32, ks*32+32) -> 16+16 packed half2
    h2 w0p[16], w1p[16];
    {
        const float* r0 = Wh + (size_t)j0 * NH + ks * 32;
        const float* r1 = r0 + NH;
        #pragma unroll
        for (int i = 0; i < 8; ++i) {
            const float4 a = *(const float4*)(r0 + 4 * i);
            const float4 c = *(const float4*)(r1 + 4 * i);
            w0p[2*i+0] = h2{(_Float16)a.x, (_Float16)a.y};
            w0p[2*i+1] = h2{(_Float16)a.z, (_Float16)a.w};
            w1p[2*i+0] = h2{(_Float16)c.x, (_Float16)c.y};
            w1p[2*i+1] = h2{(_Float16)c.z, (_Float16)c.w};
        }
    }

    if (tid < 128) {
        // h2 index tid: slice tid>>4, within tid&15
        const float2 hp = *(const float2*)(h0 + (size_t)b * NH + tid * 2);
        hb[0][(tid >> 4) * 24 + (tid & 15)] =
            h2{(_Float16)hp.x, (_Float16)hp.y};
    }

    float2 z2 = *(const float2*)(ZO + (size_t)b * NH + j0);   // t = 0
    __syncthreads();

    int cur = 0;
    for (int t = 0; t < NT; ++t) {
        // this thread's 16 h2 of h (4 x ds_read_b128, aligned, broadcast)
        h2 hh[16];
        const h2* hv = &hb[cur][ks * 24];
        #pragma unroll
        for (int i = 0; i < 4; ++i)
            *(u4*)&hh[4 * i] = *(const u4*)&hv[4 * i];

        // prefetch z for t+1 (hides under the dot)
        float2 z2n = z2;
        if (t + 1 < NT)
            z2n = *(const float2*)(ZO + ((size_t)(t + 1) * NB + b) * NH + j0);

        // dot over this thread's 32-k slice; 4 chains
        float a0 = 0.f, a1 = 0.f, c0 = 0.f, c1 = 0.f;
        #pragma unroll
        for (int i = 0; i < 8; ++i) {
            a0 = DOT2(w0p[i],     hh[i],     a0);
            a1 = DOT2(w1p[i],     hh[i],     a1);
            c0 = DOT2(w0p[i + 8], hh[i + 8], c0);
            c1 = DOT2(w1p[i + 8], hh[i + 8], c1);
        }
        float s0 = a0 + c0;
        float s1 = a1 + c1;

        // reduce the 8 k-slice partials (lanes differing in bits 0..2)
        s0 += __shfl_xor(s0, 1); s1 += __shfl_xor(s1, 1);
        s0 += __shfl_xor(s0, 2); s1 += __shfl_xor(s1, 2);
        s0 += __shfl_xor(s0, 4); s1 += __shfl_xor(s1, 4);

        if (ks == 0) {
            const float p0 = z2.x + s0;
            const float p1 = z2.y + s1;
            const float hn0 = 1.0f / (1.0f + __expf(-p0));
            const float hn1 = 1.0f / (1.0f + __expf(-p1));
            hb[cur ^ 1][(jb >> 4) * 24 + (jb & 15)] =
                h2{(_Float16)hn0, (_Float16)hn1};
            *(float2*)(ZO + ((size_t)t * NB + b) * NH + j0) =
                make_float2(hn0, hn1);
        }
        z2 = z2n;
        __syncthreads();
        cur ^= 1;
    }
}

extern "C" void kernel_launch(void* const* d_in, const int* in_sizes, int n_in,
                              void* d_out, int out_size, void* d_ws, size_t ws_size,
                              hipStream_t stream) {
    const float* X  = (const float*)d_in[0];
    const float* h0 = (const float*)d_in[1];
    const float* Wi = (const float*)d_in[2];
    const float* Wh = (const float*)d_in[3];
    const float* bh = (const float*)d_in[4];
    float* out = (float*)d_out;

    dim3 zgrid((NT * NB) / 64, NH / 64);
    zprep_kernel<<<zgrid, 256, 0, stream>>>(X, Wi, bh, out);
    rnn_step_kernel<<<NB, 1024, 0, stream>>>(out, h0, Wh);
}